// Round 10
// baseline (302.593 us; speedup 1.0000x reference)
//
#include <hip/hip_runtime.h>
#include <math.h>

// ---------------------------------------------------------------------------
// Qwen3.5 TopK Router, MI355X (gfx950).
// R19: producer/consumer wave specialization (the guide's "path past 36%").
// Six schedule variants (R13-R18) all pinned MfmaUtil at 21-23% because the
// MFMA phase and the heavy slice5-VALU stage phase live in the SAME waves,
// lockstepped by block barriers. R19 makes them concurrent BY CONSTRUCTION:
// one 1024-thread block = 16 waves, split-K by 2 over chunk parity:
//   waves 0-7  MFMA even K=64 chunks, stage odd phases' future chunks;
//   waves 8-15 MFMA odd chunks, stage even phases' future chunks.
// Phase t: MFMA-group (t&1) computes chunk t from LDS ring buf[t&3];
// the other group converts/stages chunk t+2 into buf[(t+2)&3], issues its
// B(t+1), prefetches X(t+4). ONE lgkm-only barrier per phase. Split-K
// partners (wv, wv+8) share 16 experts; exact i32 diagonals per half are
// fp64-combined and summed in LDS (every term exact -- same numerics class
// as all passing rounds).
//
// Numerics (harness-verified R11-R18):
//   x = sum_i a_i 2^-(4+7i)   (5 int8 slices, |x|<8)
//   w = sum_j c_j 2^-(9+7j)   (5 int8 slices, |w|<0.25)
//   products i+j<=4 -> exact i32 diagonal accumulators (now over K/2 each,
//   bounds halve), combined: logit = sum_s (accE_s + accO_s) * 2^-(13+7s).
//
// Fragment layouts (16x16x64 i8, verified R13-R18 passing):
//   A: lane l -> row l&15,  k = (l>>4)*16 + byte
//   B: lane l -> col l&15,  k = (l>>4)*16 + byte
//   C/D: col = l&15, row = (l>>4)*4 + reg
// ---------------------------------------------------------------------------

constexpr int T = 16384;
constexpr int D = 2048;
constexpr int E = 128;
constexpr int K = 8;

constexpr int BM = 32;        // tokens per block
constexpr int NS = 5;         // int8 slices per fp32
constexpr int NC = D / 64;    // 32 chunks of K=64 (one per phase)

typedef int i32x4 __attribute__((ext_vector_type(4)));

#define MFI8(A, B, C) C = __builtin_amdgcn_mfma_i32_16x16x64_i8(A, B, C, 0, 0, 0)

// lgkm-only barrier: LDS visibility without draining vmem queues.
#define LGKM_BARRIER() do {                                   \
    asm volatile("s_waitcnt lgkmcnt(0)" ::: "memory");        \
    __builtin_amdgcn_s_barrier();                             \
} while (0)

// Exact base-128 digit extraction: x ~= sum_s out[s] / (c * 128^s).
__device__ __forceinline__ void slice5(float x, float c, float ic, int out[NS]) {
    float r = x;
#pragma unroll
    for (int s = 0; s < NS; ++s) {
        float q = rintf(r * c);
        out[s] = (int)q;
        r = fmaf(q, -ic, r);
        c *= 128.f;
        ic *= (1.f / 128.f);
    }
}

// W(E,D) fp32 -> Ws[s][e][k] int8;  w = sum_j Ws[j][e][k] * 2^-(9+7j)
__global__ __launch_bounds__(256)
void w_slice(const float* __restrict__ W, signed char* __restrict__ Ws)
{
    const int e  = blockIdx.x >> 1;
    const int k0 = ((blockIdx.x & 1) << 10) | (threadIdx.x << 2);
    float4 v = *(const float4*)(W + (size_t)e * D + k0);
    int b0[NS], b1[NS], b2[NS], b3[NS];
    slice5(v.x, 512.f, 1.f / 512.f, b0);
    slice5(v.y, 512.f, 1.f / 512.f, b1);
    slice5(v.z, 512.f, 1.f / 512.f, b2);
    slice5(v.w, 512.f, 1.f / 512.f, b3);
#pragma unroll
    for (int s = 0; s < NS; ++s) {
        unsigned lo = __builtin_amdgcn_perm((unsigned)b1[s], (unsigned)b0[s], 0x00000400u);
        unsigned hi = __builtin_amdgcn_perm((unsigned)b3[s], (unsigned)b2[s], 0x00000400u);
        unsigned pk = __builtin_amdgcn_perm(hi, lo, 0x05040100u);
        *(int*)(Ws + (size_t)s * E * D + (size_t)e * D + k0) = (int)pk;
    }
}

// One block = 32 tokens x all 128 experts, full K. 16 waves, role-alternating
// split-K producer/consumer (see header).
__global__ __launch_bounds__(1024, 4)
void router_fused(const float* __restrict__ X,
                  const signed char* __restrict__ Ws,
                  float* __restrict__ out)
{
    // 4-deep LDS ring of chunk images: [buf][slice][tile][kgroup][tok16][16B]
    __shared__ __align__(16) signed char As[4][NS][2][4][16][16];  // 40 KB
    __shared__ double Ld[BM][E];                                   // 32 KB

    const int tid = threadIdx.x;
    const long t0 = (long)blockIdx.x * BM;

    const int l   = tid & 63;
    const int wv  = tid >> 6;     // 0..15
    const int grp = wv >> 3;      // 0: MFMA even chunks; 1: odd chunks
    const int er  = l & 15;
    const int kg  = l >> 4;

    // staging identity (both groups use the same mapping on their own 512)
    const int s_tid = tid & 511;
    const int ar    = s_tid >> 4;           // token 0..31
    const int koff  = (s_tid & 15) << 2;    // 0..60
    const float* Xp = X + (t0 + ar) * (long)D + koff;

    // B pointers: waves wv and wv+8 own experts [(wv&7)*16, +16)
    const size_t wbase = (size_t)((wv & 7) * 16 + er) * D + (size_t)kg * 16;
    const signed char* Wq0 = Ws + 0UL * E * D + wbase;
    const signed char* Wq1 = Ws + 1UL * E * D + wbase;
    const signed char* Wq2 = Ws + 2UL * E * D + wbase;
    const signed char* Wq3 = Ws + 3UL * E * D + wbase;
    const signed char* Wq4 = Ws + 4UL * E * D + wbase;

    const int loff = l * 16;    // A-fragment lane offset within a chunk image

    i32x4 e0 = {}, e1 = {}, e2 = {}, e3 = {}, e4 = {};  // tile 0 diagonals
    i32x4 f0 = {}, f1 = {}, f2 = {}, f3 = {}, f4 = {};  // tile 1 diagonals
    i32x4 bc0, bc1, bc2, bc3, bc4;                      // B for my next chunk

    // convert one float4 -> 5 packed slice-dwords into ring buffer `buf`
    auto stageChunk = [&](const float4& v, int buf) {
        int q0[NS], q1[NS], q2[NS], q3[NS];
        slice5(v.x, 16.f, 1.f / 16.f, q0);
        slice5(v.y, 16.f, 1.f / 16.f, q1);
        slice5(v.z, 16.f, 1.f / 16.f, q2);
        slice5(v.w, 16.f, 1.f / 16.f, q3);
        int* dst = (int*)&As[buf][0][ar >> 4][koff >> 4][ar & 15][koff & 15];
#pragma unroll
        for (int s = 0; s < NS; ++s) {
            unsigned lo = __builtin_amdgcn_perm((unsigned)q1[s], (unsigned)q0[s], 0x00000400u);
            unsigned hi = __builtin_amdgcn_perm((unsigned)q3[s], (unsigned)q2[s], 0x00000400u);
            unsigned pk = __builtin_amdgcn_perm(hi, lo, 0x05040100u);
            dst[s * 512] = (int)pk;   // slice stride = 2048 B
        }
    };

    // 30 mfma for one K=64 chunk: a-index-major, both tiles interleaved
    auto chunkMM = [&](const signed char* ap,
                       const i32x4& b0, const i32x4& b1, const i32x4& b2,
                       const i32x4& b3, const i32x4& b4) {
        i32x4 at0, at1;
        __builtin_amdgcn_s_setprio(1);
        at0 = *(const i32x4*)(ap);           at1 = *(const i32x4*)(ap + 1024);
        MFI8(at0, b0, e0); MFI8(at0, b1, e1); MFI8(at0, b2, e2); MFI8(at0, b3, e3); MFI8(at0, b4, e4);
        MFI8(at1, b0, f0); MFI8(at1, b1, f1); MFI8(at1, b2, f2); MFI8(at1, b3, f3); MFI8(at1, b4, f4);
        at0 = *(const i32x4*)(ap + 2048);    at1 = *(const i32x4*)(ap + 3072);
        MFI8(at0, b0, e1); MFI8(at0, b1, e2); MFI8(at0, b2, e3); MFI8(at0, b3, e4);
        MFI8(at1, b0, f1); MFI8(at1, b1, f2); MFI8(at1, b2, f3); MFI8(at1, b3, f4);
        at0 = *(const i32x4*)(ap + 4096);    at1 = *(const i32x4*)(ap + 5120);
        MFI8(at0, b0, e2); MFI8(at0, b1, e3); MFI8(at0, b2, e4);
        MFI8(at1, b0, f2); MFI8(at1, b1, f3); MFI8(at1, b2, f4);
        at0 = *(const i32x4*)(ap + 6144);    at1 = *(const i32x4*)(ap + 7168);
        MFI8(at0, b0, e3); MFI8(at0, b1, e4);
        MFI8(at1, b0, f3); MFI8(at1, b1, f4);
        at0 = *(const i32x4*)(ap + 8192);    at1 = *(const i32x4*)(ap + 9216);
        MFI8(at0, b0, e4);
        MFI8(at1, b0, f4);
        __builtin_amdgcn_s_setprio(0);
    };

    // ---- prologue ----
    // all 1024 threads stage chunks 0,1 (one float4 each)
    {
        float4 v = *(const float4*)(Xp + (tid >> 9) * 64);
        stageChunk(v, tid >> 9);
    }
    // my first MFMA chunk is `grp`: preload its B
    bc0 = *(const i32x4*)(Wq0 + grp * 64);
    bc1 = *(const i32x4*)(Wq1 + grp * 64);
    bc2 = *(const i32x4*)(Wq2 + grp * 64);
    bc3 = *(const i32x4*)(Wq3 + grp * 64);
    bc4 = *(const i32x4*)(Wq4 + grp * 64);
    // my first stage phase handles chunk 3-grp+... : grp0 stages chunk 3 (t=1),
    // grp1 stages chunk 2 (t=0). Preload its X.
    float4 xv = *(const float4*)(Xp + (3 - grp) * 64);
    LGKM_BARRIER();

    // ---- main loop: 32 phases, one K=64 chunk each, ONE barrier/phase ----
    for (int t = 0; t < NC; ++t) {
        if (grp == (t & 1)) {
            // MFMA role: chunk t from ring buf[t&3], B preloaded last phase
            const signed char* ap =
                (const signed char*)&As[t & 3][0][0][0][0][0] + loff;
            chunkMM(ap, bc0, bc1, bc2, bc3, bc4);
        } else {
            // producer role
            float4 xn = xv;
            if (t + 4 < NC) xn = *(const float4*)(Xp + (t + 4) * 64);  // X for my stage at t+2
            if (t + 1 < NC) {                                          // B for my MFMA at t+1
                const long kc = (long)(t + 1) * 64;
                bc0 = *(const i32x4*)(Wq0 + kc);
                bc1 = *(const i32x4*)(Wq1 + kc);
                bc2 = *(const i32x4*)(Wq2 + kc);
                bc3 = *(const i32x4*)(Wq3 + kc);
                bc4 = *(const i32x4*)(Wq4 + kc);
            }
            __builtin_amdgcn_sched_barrier(0);
            if (t + 2 < NC) stageChunk(xv, (t + 2) & 3);               // convert + ds_write
            xv = xn;
        }
        // ring hazards separated by >=2 barriers (write t+2 vs read t);
        // vmem (B/X) deliberately left in flight.
        LGKM_BARRIER();
    }

    // ---- split-K merge: exact fp64 partials summed in LDS ----
    double g0[4], g1[4];
#pragma unroll
    for (int r = 0; r < 4; ++r) {
        g0[r] = (double)e0[r] * 0x1p-13 + (double)e1[r] * 0x1p-20
              + (double)e2[r] * 0x1p-27 + (double)e3[r] * 0x1p-34
              + (double)e4[r] * 0x1p-41;
        g1[r] = (double)f0[r] * 0x1p-13 + (double)f1[r] * 0x1p-20
              + (double)f2[r] * 0x1p-27 + (double)f3[r] * 0x1p-34
              + (double)f4[r] * 0x1p-41;
    }
    const int col = (wv & 7) * 16 + er;
    if (grp == 0) {
#pragma unroll
        for (int r = 0; r < 4; ++r) {
            Ld[kg * 4 + r][col]      = g0[r];
            Ld[kg * 4 + r + 16][col] = g1[r];
        }
    }
    LGKM_BARRIER();
    if (grp == 1) {
#pragma unroll
        for (int r = 0; r < 4; ++r) {
            Ld[kg * 4 + r][col]      += g0[r];
            Ld[kg * 4 + r + 16][col] += g1[r];
        }
    }
    LGKM_BARRIER();

    // ---- epilogue: verified R11/R13 logic; tids 0..511 = 32 tokens x 16 ----
    if (tid < 512) {
        float* outL  = out;
        float* outWt = out + (long)T * E;
        float* outId = outWt + (long)T * K;
        const int tx = tid & 15;
        const int tt = tid >> 4;            // token 0..31
        const long t = t0 + tt;

        double acc[8];
#pragma unroll
        for (int j = 0; j < 8; ++j) acc[j] = Ld[tt][(tx << 3) + j];

        double m = acc[0];
#pragma unroll
        for (int j = 1; j < 8; ++j) m = fmax(m, acc[j]);
#pragma unroll
        for (int mask = 1; mask <= 8; mask <<= 1)
            m = fmax(m, __shfl_xor(m, mask, 64));

        float e[8]; float s = 0.f;
#pragma unroll
        for (int j = 0; j < 8; ++j) { e[j] = __expf((float)(acc[j] - m)); s += e[j]; }
#pragma unroll
        for (int mask = 1; mask <= 8; mask <<= 1)
            s += __shfl_xor(s, mask, 64);
        const float inv = 1.f / s;

        float4 st0 = {e[0] * inv, e[1] * inv, e[2] * inv, e[3] * inv};
        float4 st1 = {e[4] * inv, e[5] * inv, e[6] * inv, e[7] * inv};
        *(float4*)&outL[t * E + (tx << 3)]     = st0;
        *(float4*)&outL[t * E + (tx << 3) + 4] = st1;

        // top-8 on fp64 logits (value desc, index asc) == jax.lax.top_k order
        double v[8];
#pragma unroll
        for (int j = 0; j < 8; ++j) v[j] = acc[j];

        float pk[K]; int ik[K]; float tsum = 0.f;
#pragma unroll
        for (int r = 0; r < K; ++r) {
            double bv = -1.0e300; int bi = 0x7fffffff;
#pragma unroll
            for (int j = 0; j < 8; ++j) {
                const int idx = (tx << 3) + j;
                const bool better = (v[j] > bv) || (v[j] == bv && idx < bi);
                bv = better ? v[j] : bv;
                bi = better ? idx : bi;
            }
#pragma unroll
            for (int mask = 1; mask <= 8; mask <<= 1) {
                const double ov = __shfl_xor(bv, mask, 64);
                const int    oi = __shfl_xor(bi, mask, 64);
                const bool better = (ov > bv) || (ov == bv && oi < bi);
                bv = better ? ov : bv;
                bi = better ? oi : bi;
            }
            const float pw = __expf((float)(bv - m)) * inv;
            pk[r] = pw; ik[r] = bi; tsum += pw;
            // static-index knockout (dynamic v[bi&7] would force scratch)
            const bool own  = ((bi >> 3) == tx);
            const int  slot = bi & 7;
#pragma unroll
            for (int j = 0; j < 8; ++j)
                v[j] = (own && j == slot) ? -1.0e300 : v[j];
        }

        if (tx == 0) {
            const float rinv = 1.f / tsum;
#pragma unroll
            for (int r = 0; r < K; ++r) {
                outWt[t * K + r] = pk[r] * rinv;
                outId[t * K + r] = (float)ik[r];
            }
        }
    }
}

extern "C" void kernel_launch(void* const* d_in, const int* in_sizes, int n_in,
                              void* d_out, int out_size, void* d_ws, size_t ws_size,
                              hipStream_t stream)
{
    const float* X = (const float*)d_in[0];
    const float* W = (const float*)d_in[1];
    float* out = (float*)d_out;
    signed char* Ws = (signed char*)d_ws;   // needs NS*E*D = 1.31 MB (<< ws)

    w_slice<<<dim3(E * 2), dim3(256), 0, stream>>>(W, Ws);
    router_fused<<<dim3(T / BM), dim3(1024), 0, stream>>>(X, Ws, out);
}